// Round 12
// baseline (726.538 us; speedup 1.0000x reference)
//
#include <hip/hip_runtime.h>
#include <hip/hip_bf16.h>

#define BB 256
#define TT 64
#define XD 512
#define CCG 256
#define DINk 768
#define HH 1024
#define G4 4096
#define NTAG 512

typedef float f32x4 __attribute__((ext_vector_type(4)));
typedef short s16x8 __attribute__((ext_vector_type(8)));
typedef short s16x4 __attribute__((ext_vector_type(4)));

// ---- workspace layout (bytes) ----
#define WS_HS    0ull                                 // [TT+1][B][H] bf16 (slot0=h0)
#define WS_XBASE (WS_HS + (size_t)(TT+1)*BB*HH*2)
#define WS_EPROJ (WS_XBASE + (size_t)BB*G4*4)
#define WS_WIH   (WS_EPROJ + (size_t)NTAG*G4*4)
#define WS_WOUT  (WS_WIH + (size_t)G4*DINk*2)
#define WS_XBF   (WS_WOUT + (size_t)NTAG*HH*2)
#define WS_EMBBF (WS_XBF + (size_t)BB*XD*2)
#define WS_CNT   (WS_EMBBF + (size_t)NTAG*CCG*2)      // 256 flag ints
#define WS_ACC   (WS_CNT + 1024)
#define WS_FLAG  (WS_ACC + 64)
#define WS_XPROJ (WS_FLAG + 64)                       // [T][4096 gc][256 b] bf16

static __device__ __forceinline__ short f2bf(float f) {
  __hip_bfloat16 h = __float2bfloat16(f);
  return __builtin_bit_cast(short, h);
}
static __device__ __forceinline__ float bf2f(unsigned short u) {
  unsigned x = ((unsigned)u) << 16;
  return __builtin_bit_cast(float, x);
}
static __device__ __forceinline__ void store_dword_cc(void* p, unsigned v) {
  asm volatile("global_store_dword %0, %1, off sc0 sc1" :: "v"(p), "v"(v) : "memory");
}
static __device__ __forceinline__ void store_short_cc(void* p, unsigned v) {
  asm volatile("global_store_short %0, %1, off sc0 sc1" :: "v"(p), "v"(v) : "memory");
}
static __device__ __forceinline__ int load_int_cc(const void* p) {
  int r;
  asm volatile("global_load_dword %0, %1, off sc0 sc1\n\ts_waitcnt vmcnt(0)"
               : "=v"(r) : "v"(p) : "memory");
  return r;
}
static __device__ __forceinline__ float fsig(float x) {
  return __builtin_amdgcn_rcpf(1.f + __expf(-x));
}
static __device__ __forceinline__ float ftanh(float x) {
  return 1.f - 2.f * __builtin_amdgcn_rcpf(1.f + __expf(2.f * x));
}

__global__ void k_f2bf8(const float* __restrict__ in, short* __restrict__ out, int n8) {
  int i = blockIdx.x * blockDim.x + threadIdx.x;
  if (i >= n8) return;
  size_t idx = (size_t)i * 8;
  float4 a = *(const float4*)(in + idx);
  float4 b = *(const float4*)(in + idx + 4);
  s16x8 o;
  o[0]=f2bf(a.x); o[1]=f2bf(a.y); o[2]=f2bf(a.z); o[3]=f2bf(a.w);
  o[4]=f2bf(b.x); o[5]=f2bf(b.y); o[6]=f2bf(b.z); o[7]=f2bf(b.w);
  *(s16x8*)(out + idx) = o;
}

__global__ void k_init(const float* __restrict__ h0, const int* __restrict__ mask_as_int,
                       char* __restrict__ ws) {
  int tid = blockIdx.x * blockDim.x + threadIdx.x;
  short* hb0 = (short*)(ws + WS_HS);
  for (int i = tid; i < BB * HH; i += gridDim.x * blockDim.x) hb0[i] = f2bf(h0[i]);
  if (blockIdx.x == 0) {
    int* cnt = (int*)(ws + WS_CNT);
    for (int i = threadIdx.x; i < 256; i += blockDim.x) cnt[i] = 0;
    int v = 0;
    for (int i = threadIdx.x; i < 4096; i += blockDim.x) v |= (mask_as_int[i] & ~1);
    __shared__ int red[256];
    red[threadIdx.x] = v;
    __syncthreads();
    if (threadIdx.x == 0) {
      int a = 0;
      for (int j = 0; j < 256; j++) a |= red[j];
      ((int*)(ws + WS_FLAG))[0] = (a != 0) ? 1 : 0;
      float* acc = (float*)(ws + WS_ACC);
      acc[0] = 0.f; acc[1] = 0.f;
    }
  }
}

// ---- bf16 MFMA GEMM: C[M][N] = A[M][K] * Bm[N][K]^T (+bias1+bias2), bf16 out ----
__global__ __launch_bounds__(256) void k_gemm(const short* __restrict__ A, int lda,
    const short* __restrict__ Bm, int ldb, int bcol0,
    short* __restrict__ C, int ldc, int ksteps,
    const float* __restrict__ bias1, const float* __restrict__ bias2) {
  int w = threadIdx.x >> 6, l = threadIdx.x & 63;
  int lc = l & 15, lq = l >> 4;
  int arow = blockIdx.x * 64 + w * 16 + lc;
  f32x4 acc[4];
  const f32x4 z = {0.f, 0.f, 0.f, 0.f};
#pragma unroll
  for (int i = 0; i < 4; i++) acc[i] = z;
  const short* ap = A + (size_t)arow * lda + lq * 8;
  for (int kk = 0; kk < ksteps; ++kk) {
    s16x8 a = *(const s16x8*)(ap + kk * 32);
#pragma unroll
    for (int nt = 0; nt < 4; ++nt) {
      int brow = blockIdx.y * 64 + nt * 16 + lc;
      s16x8 b = *(const s16x8*)(Bm + (size_t)brow * ldb + bcol0 + kk * 32 + lq * 8);
      acc[nt] = __builtin_amdgcn_mfma_f32_16x16x32_bf16(a, b, acc[nt], 0, 0, 0);
    }
  }
#pragma unroll
  for (int nt = 0; nt < 4; ++nt) {
    int col = blockIdx.y * 64 + nt * 16 + lc;
    float badd = (bias1 ? bias1[col] : 0.f) + (bias2 ? bias2[col] : 0.f);
#pragma unroll
    for (int j = 0; j < 4; j++) {
      int r = blockIdx.x * 64 + w * 16 + lq * 4 + j;
      C[(size_t)r * ldc + col] = f2bf(acc[nt][j] + badd);
    }
  }
}

// xproj_t[t][gc][b] = xbase[b][gc] + eproj[tok(b,t)][gc]   (bf16, transposed)
__global__ __launch_bounds__(256) void k_xproj_t(const short* __restrict__ xb,
    const short* __restrict__ ep, const int* __restrict__ atruth,
    short* __restrict__ out) {
  __shared__ short tile[64 * 264];
  const int cc = blockIdx.x, g = blockIdx.y, t = blockIdx.z;
  const int b = threadIdx.x;
  const int tok = (t == 0) ? 0 : atruth[b * TT + t - 1];
  const int gc0 = g * 1024 + cc * 64;
  const short* xs = xb + (size_t)b * G4 + gc0;
  const short* es = ep + (size_t)tok * G4 + gc0;
#pragma unroll
  for (int i = 0; i < 64; i += 8) {
    s16x8 xv = *(const s16x8*)(xs + i);
    s16x8 ev = *(const s16x8*)(es + i);
#pragma unroll
    for (int j = 0; j < 8; ++j)
      tile[(i + j) * 264 + b] = f2bf(bf2f((unsigned short)xv[j]) + bf2f((unsigned short)ev[j]));
  }
  __syncthreads();
  const int c = threadIdx.x >> 2, b0 = (threadIdx.x & 3) * 64;
  short* dst = out + ((size_t)t * G4 + gc0 + c) * BB + b0;
  const short* src = tile + c * 264 + b0;
#pragma unroll
  for (int i = 0; i < 64; i += 8) *(s16x8*)(dst + i) = *(const s16x8*)(src + i);
}

// ---- persistent LSTM recurrence ----
// 256 WGs (1/CU), 512 threads. Group = 64 WGs over 64 batch rows (2 XCDs);
// each WG owns 16 hidden cols. Waves: (wy 0..3 row-slab 16) x (kh 0..1 k-half).
// Proven round-4 structure/protocol. ONLY change: A-fragments prefetched with
// inline-asm global_load_dwordx4 into areg[16] (cannot be sunk by compiler) +
// single vmcnt(0) — 16 IF$ round trips collapse to ~1.
__global__ __launch_bounds__(512) void k_lstm(const float* __restrict__ Whh,
    const short* __restrict__ xproj, const float* __restrict__ c0,
    char* __restrict__ ws) {
  extern __shared__ char sm[];
  float* part = (float*)(sm + 131072);        // [4 wy][64 lane][20 pad] f32
  const int bid = blockIdx.x;
  const int xcd = bid & 7, slot = bid >> 3;
  const int mg = xcd >> 1;                    // batch group 0..3
  const int hb = slot * 2 + (xcd & 1);        // hidden block 0..63
  const int wgid = (xcd & 1) * 32 + slot;     // id within group 0..63
  const int tid = threadIdx.x;
  const int w = tid >> 6, l = tid & 63;
  const int lc = l & 15, lq = l >> 4;
  const int wy = w & 3, kh = w >> 2;          // row-slab(16) / k-half(512)

  // stage W_hh slice -> LDS bf16 swizzled: row r=g*16+rl at r*2048, byte k ^ ((rl&7)<<4)
  {
    const int r = tid >> 3, q = tid & 7;
    const int g = r >> 4, rl = r & 15;
    const float* src = Whh + (size_t)(g * HH + hb * 16 + rl) * HH + q * 128;
    const int swz = (rl & 7) << 4;
    char* dst = sm + r * 2048;
#pragma unroll
    for (int i = 0; i < 128; i += 8) {
      float4 f0 = *(const float4*)(src + i);
      float4 f1 = *(const float4*)(src + i + 4);
      s16x8 o;
      o[0]=f2bf(f0.x); o[1]=f2bf(f0.y); o[2]=f2bf(f0.z); o[3]=f2bf(f0.w);
      o[4]=f2bf(f1.x); o[5]=f2bf(f1.y); o[6]=f2bf(f1.z); o[7]=f2bf(f1.w);
      int koff = (q * 128 + i) * 2;
      *(s16x8*)(dst + (koff ^ swz)) = o;
    }
  }

  const int colbase = hb * 16;
  short* hs = (short*)(ws + WS_HS);
  int* flags = (int*)(ws + WS_CNT);
  const int swzl = (lc & 7) << 4;
  const int row0 = mg * 64 + wy * 16;

  // c-state (kh=0 lanes): cell (row0 + lq*4 + j, colbase + lc)
  float cst[4];
  s16x4 xg0, xg1, xg2, xg3, xn0, xn1, xn2, xn3;
  if (kh == 0) {
#pragma unroll
    for (int j = 0; j < 4; ++j)
      cst[j] = c0[(size_t)(row0 + lq * 4 + j) * HH + colbase + lc];
    const short* xp = xproj + ((size_t)colbase + lc) * BB + row0 + lq * 4;
    xg0 = *(const s16x4*)(xp);
    xg1 = *(const s16x4*)(xp + (size_t)1024 * BB);
    xg2 = *(const s16x4*)(xp + (size_t)2048 * BB);
    xg3 = *(const s16x4*)(xp + (size_t)3072 * BB);
  }
  float* pslot = part + ((size_t)wy * 64 + l) * 20;
  __syncthreads();

  for (int t = 0; t < TT; ++t) {
    if (t && w == 0) {  // wave-0 poll: all 64 group flags >= t
      const int* f = flags + mg * 64 + l;
      for (;;) {
        int v = load_int_cc(f);
        if (__all(v >= t)) break;
        __builtin_amdgcn_s_sleep(1);
      }
    }
    __syncthreads();  // B1: step-t h visible

    // prefetch next step's xproj into regs (issued first; overlaps with A-loads)
    if (kh == 0 && t + 1 < TT) {
      const short* xp = xproj + ((size_t)(t + 1) * G4 + colbase + lc) * BB + row0 + lq * 4;
      xn0 = *(const s16x4*)(xp);
      xn1 = *(const s16x4*)(xp + (size_t)1024 * BB);
      xn2 = *(const s16x4*)(xp + (size_t)2048 * BB);
      xn3 = *(const s16x4*)(xp + (size_t)3072 * BB);
    }

    // ---- A prefetch: 16 fragments via inline asm (cannot be sunk), 1 vmcnt ----
    const short* arowp = hs + (size_t)t * (BB * HH) + (size_t)(row0 + lc) * HH + kh * 512 + lq * 8;
    s16x8 areg[16];
#pragma unroll
    for (int kk = 0; kk < 16; ++kk)
      asm volatile("global_load_dwordx4 %0, %1, off"
                   : "=v"(areg[kk]) : "v"(arowp + kk * 32) : "memory");
    asm volatile("s_waitcnt vmcnt(0)" ::: "memory");

    // MFMA: 4 gates x 16 rows x 16 cols over k-half kh
    const f32x4 z = {0.f, 0.f, 0.f, 0.f};
    f32x4 acc0 = z, acc1 = z, acc2 = z, acc3 = z;
#pragma unroll
    for (int kk = 0; kk < 16; ++kk) {
      const int kx = (((kh * 16 + kk) * 64) + lq * 16) ^ swzl;
      const char* bp = sm + lc * 2048 + kx;
      acc0 = __builtin_amdgcn_mfma_f32_16x16x32_bf16(areg[kk], *(const s16x8*)(bp), acc0, 0, 0, 0);
      acc1 = __builtin_amdgcn_mfma_f32_16x16x32_bf16(areg[kk], *(const s16x8*)(bp + 16 * 2048), acc1, 0, 0, 0);
      acc2 = __builtin_amdgcn_mfma_f32_16x16x32_bf16(areg[kk], *(const s16x8*)(bp + 32 * 2048), acc2, 0, 0, 0);
      acc3 = __builtin_amdgcn_mfma_f32_16x16x32_bf16(areg[kk], *(const s16x8*)(bp + 48 * 2048), acc3, 0, 0, 0);
    }

    // partial exchange: kh=1 writes (stride-20 pad f32x4s) — round-4 proven
    if (kh == 1) {
      *(f32x4*)(pslot) = acc0;
      *(f32x4*)(pslot + 4) = acc1;
      *(f32x4*)(pslot + 8) = acc2;
      *(f32x4*)(pslot + 12) = acc3;
    }
    __syncthreads();  // B2: partials ready

    if (kh == 0) {
      acc0 += *(const f32x4*)(pslot);
      acc1 += *(const f32x4*)(pslot + 4);
      acc2 += *(const f32x4*)(pslot + 8);
      acc3 += *(const f32x4*)(pslot + 12);
      short* hrow = hs + (size_t)(t + 1) * (BB * HH) +
                    (size_t)(row0 + lq * 4) * HH + colbase + lc;
#pragma unroll
      for (int j = 0; j < 4; ++j) {
        float pi = acc0[j] + bf2f((unsigned short)xg0[j]);
        float pf = acc1[j] + bf2f((unsigned short)xg1[j]);
        float pg = acc2[j] + bf2f((unsigned short)xg2[j]);
        float po = acc3[j] + bf2f((unsigned short)xg3[j]);
        float cv = fsig(pf) * cst[j] + fsig(pi) * ftanh(pg);
        cst[j] = cv;
        store_short_cc(hrow + (size_t)j * HH, (unsigned)(unsigned short)f2bf(fsig(po) * ftanh(cv)));
      }
      xg0 = xn0; xg1 = xn1; xg2 = xn2; xg3 = xn3;
    }
    asm volatile("s_waitcnt vmcnt(0)" ::: "memory");  // each wave drains own stores
    __syncthreads();                                   // B3: all drained
    if (tid == 0 && t < TT - 1) store_dword_cc(flags + mg * 64 + wgid, t + 1);
  }
}

// ---- logits + fused log-softmax + masked NLL partial sums ----
__global__ __launch_bounds__(256, 1) void k_logits(const short* __restrict__ hsb,
    const short* __restrict__ Wo, const float* __restrict__ bout,
    const int* __restrict__ atruth, const void* __restrict__ maskp,
    char* __restrict__ ws) {
  extern __shared__ char sm[];
  const int tid = threadIdx.x;
  const int w = tid >> 6, l = tid & 63;
  const int lc = l & 15, lq = l >> 4;
  const int rowbase = blockIdx.x * 64 + w * 16;
  f32x4 acc[32];
#pragma unroll
  for (int nt = 0; nt < 32; ++nt) {
    float bv = bout[nt * 16 + lc];
    f32x4 tmp = {bv, bv, bv, bv};
    acc[nt] = tmp;
  }
  const int swzl = (lc & 7) << 4;
  for (int kb = 0; kb < 16; ++kb) {
    __syncthreads();
    {
      const int r0 = tid >> 3, q = tid & 7;
#pragma unroll
      for (int i = 0; i < 16; i++) {
        int r = r0 + 32 * i;
        s16x8 v = *(const s16x8*)(Wo + (size_t)r * HH + kb * 64 + q * 8);
        *(s16x8*)(sm + r * 128 + ((q * 16) ^ ((r & 7) << 4))) = v;
      }
    }
    __syncthreads();
#pragma unroll
    for (int ks = 0; ks < 2; ++ks) {
      s16x8 a = *(const s16x8*)(hsb + (size_t)(rowbase + lc) * HH + kb * 64 + ks * 32 + lq * 8);
      const int kx = (ks * 64 + lq * 16) ^ swzl;
#pragma unroll
      for (int nt = 0; nt < 32; ++nt) {
        s16x8 b = *(const s16x8*)(sm + (nt * 16 + lc) * 128 + kx);
        acc[nt] = __builtin_amdgcn_mfma_f32_16x16x32_bf16(a, b, acc[nt], 0, 0, 0);
      }
    }
  }
  const int bytemode = ((const int*)(ws + WS_FLAG))[0];
  const unsigned char* mb = (const unsigned char*)maskp;
  const int* mi = (const int*)maskp;
  float nlls = 0.f, cnts = 0.f;
#pragma unroll
  for (int j = 0; j < 4; j++) {
    int gr = rowbase + lq * 4 + j;
    int tt = gr >> 8, b = gr & 255;
    float m = -1e30f;
#pragma unroll
    for (int nt = 0; nt < 32; ++nt) m = fmaxf(m, acc[nt][j]);
    m = fmaxf(m, __shfl_xor(m, 1)); m = fmaxf(m, __shfl_xor(m, 2));
    m = fmaxf(m, __shfl_xor(m, 4)); m = fmaxf(m, __shfl_xor(m, 8));
    float s = 0.f;
#pragma unroll
    for (int nt = 0; nt < 32; ++nt) s += __expf(acc[nt][j] - m);
    s += __shfl_xor(s, 1); s += __shfl_xor(s, 2);
    s += __shfl_xor(s, 4); s += __shfl_xor(s, 8);
    float lse = m + __logf(s);
    int tg = atruth[b * TT + tt];
    int mk = bytemode ? (int)mb[b * TT + tt] : mi[b * TT + tt];
    if (((tg & 15) == lc) && mk) {
      float tl = 0.f;
#pragma unroll
      for (int nt = 0; nt < 32; ++nt) if (nt == (tg >> 4)) tl = acc[nt][j];
      nlls += (lse - tl);
    }
    if (lc == 0 && mk) cnts += 1.f;
  }
#pragma unroll
  for (int off = 1; off < 64; off <<= 1) {
    nlls += __shfl_xor(nlls, off);
    cnts += __shfl_xor(cnts, off);
  }
  if (l == 0) {
    float* accf = (float*)(ws + WS_ACC);
    atomicAdd(&accf[0], nlls);
    atomicAdd(&accf[1], cnts);
  }
}

__global__ void k_final(const char* __restrict__ ws, float* __restrict__ out) {
  const float* accf = (const float*)(ws + WS_ACC);
  out[0] = accf[0] / accf[1];
}

extern "C" void kernel_launch(void* const* d_in, const int* in_sizes, int n_in,
                              void* d_out, int out_size, void* d_ws, size_t ws_size,
                              hipStream_t stream) {
  const float* x      = (const float*)d_in[0];
  const int*   atruth = (const int*)d_in[1];
  const void*  amask  = d_in[2];
  const float* emb    = (const float*)d_in[3];
  const float* W_ih   = (const float*)d_in[4];
  const float* W_hh   = (const float*)d_in[5];
  const float* b_ih   = (const float*)d_in[6];
  const float* b_hh   = (const float*)d_in[7];
  const float* W_out  = (const float*)d_in[8];
  const float* b_out  = (const float*)d_in[9];
  const float* h0     = (const float*)d_in[10];
  const float* c0     = (const float*)d_in[11];
  char* ws = (char*)d_ws;
  float* out = (float*)d_out;

  hipFuncSetAttribute((const void*)k_lstm, hipFuncAttributeMaxDynamicSharedMemorySize, 151552);
  hipFuncSetAttribute((const void*)k_logits, hipFuncAttributeMaxDynamicSharedMemorySize, 65536);

  k_f2bf8<<<dim3((G4 * DINk / 8 + 255) / 256), 256, 0, stream>>>(W_ih, (short*)(ws + WS_WIH), G4 * DINk / 8);
  k_f2bf8<<<dim3((NTAG * HH / 8 + 255) / 256), 256, 0, stream>>>(W_out, (short*)(ws + WS_WOUT), NTAG * HH / 8);
  k_f2bf8<<<dim3((BB * XD / 8 + 255) / 256), 256, 0, stream>>>(x, (short*)(ws + WS_XBF), BB * XD / 8);
  k_f2bf8<<<dim3((NTAG * CCG / 8 + 255) / 256), 256, 0, stream>>>(emb, (short*)(ws + WS_EMBBF), NTAG * CCG / 8);

  k_init<<<64, 256, 0, stream>>>(h0, (const int*)amask, ws);

  // xbase = x @ W_ih[:, :512]^T + b_ih + b_hh    [256, 4096] bf16
  k_gemm<<<dim3(4, 64), 256, 0, stream>>>((short*)(ws + WS_XBF), XD, (short*)(ws + WS_WIH), DINk, 0,
                                          (short*)(ws + WS_XBASE), G4, XD / 32, b_ih, b_hh);
  // eproj = emb @ W_ih[:, 512:]^T                [512, 4096] bf16
  k_gemm<<<dim3(8, 64), 256, 0, stream>>>((short*)(ws + WS_EMBBF), CCG, (short*)(ws + WS_WIH), DINk, XD,
                                          (short*)(ws + WS_EPROJ), G4, CCG / 32, nullptr, nullptr);

  // xproj_t[t][gc][b] = xbase[b][gc] + eproj[prev_tok][gc]  (bf16 transposed)
  k_xproj_t<<<dim3(16, 4, 64), 256, 0, stream>>>((const short*)(ws + WS_XBASE),
                                                 (const short*)(ws + WS_EPROJ), atruth,
                                                 (short*)(ws + WS_XPROJ));

  k_lstm<<<256, 512, 151552, stream>>>(W_hh, (const short*)(ws + WS_XPROJ), c0, ws);

  k_logits<<<256, 256, 65536, stream>>>((short*)(ws + WS_HS) + BB * HH, (short*)(ws + WS_WOUT), b_out,
                                        atruth, amask, ws);
  k_final<<<1, 1, 0, stream>>>(ws, out);
}

// Round 13
// 548.406 us; speedup vs baseline: 1.3248x; 1.3248x over previous
//
#include <hip/hip_runtime.h>
#include <hip/hip_bf16.h>

#define BB 256
#define TT 64
#define XD 512
#define CCG 256
#define DINk 768
#define HH 1024
#define G4 4096
#define NTAG 512

typedef float f32x4 __attribute__((ext_vector_type(4)));
typedef short s16x8 __attribute__((ext_vector_type(8)));

// ---- workspace layout (bytes) ----
#define WS_HS    0ull                                 // [TT+1][B][H] bf16 (slot0=h0)
#define WS_XBASE (WS_HS + (size_t)(TT+1)*BB*HH*2)     // xbase bf16 [256][4096] (+biases)
#define WS_EPROJ (WS_XBASE + (size_t)BB*G4*4)         // eproj bf16 [512][4096]
#define WS_WIH   (WS_EPROJ + (size_t)NTAG*G4*4)
#define WS_WOUT  (WS_WIH + (size_t)G4*DINk*2)
#define WS_XBF   (WS_WOUT + (size_t)NTAG*HH*2)
#define WS_EMBBF (WS_XBF + (size_t)BB*XD*2)
#define WS_CNT   (WS_EMBBF + (size_t)NTAG*CCG*2)      // 256 flag ints
#define WS_ACC   (WS_CNT + 1024)
#define WS_FLAG  (WS_ACC + 64)

static __device__ __forceinline__ short f2bf(float f) {
  __hip_bfloat16 h = __float2bfloat16(f);
  return __builtin_bit_cast(short, h);
}
static __device__ __forceinline__ float bf2f(unsigned short u) {
  unsigned x = ((unsigned)u) << 16;
  return __builtin_bit_cast(float, x);
}
static __device__ __forceinline__ void store_dword_cc(void* p, unsigned v) {
  asm volatile("global_store_dword %0, %1, off sc0 sc1" :: "v"(p), "v"(v) : "memory");
}
static __device__ __forceinline__ void store_short_cc(void* p, unsigned v) {
  asm volatile("global_store_short %0, %1, off sc0 sc1" :: "v"(p), "v"(v) : "memory");
}
static __device__ __forceinline__ int load_int_cc(const void* p) {
  int r;
  asm volatile("global_load_dword %0, %1, off sc0 sc1\n\ts_waitcnt vmcnt(0)"
               : "=v"(r) : "v"(p) : "memory");
  return r;
}
static __device__ __forceinline__ float fsig(float x) {
  return __builtin_amdgcn_rcpf(1.f + __expf(-x));
}
static __device__ __forceinline__ float ftanh(float x) {
  return 1.f - 2.f * __builtin_amdgcn_rcpf(1.f + __expf(2.f * x));
}

__global__ void k_f2bf8(const float* __restrict__ in, short* __restrict__ out, int n8) {
  int i = blockIdx.x * blockDim.x + threadIdx.x;
  if (i >= n8) return;
  size_t idx = (size_t)i * 8;
  float4 a = *(const float4*)(in + idx);
  float4 b = *(const float4*)(in + idx + 4);
  s16x8 o;
  o[0]=f2bf(a.x); o[1]=f2bf(a.y); o[2]=f2bf(a.z); o[3]=f2bf(a.w);
  o[4]=f2bf(b.x); o[5]=f2bf(b.y); o[6]=f2bf(b.z); o[7]=f2bf(b.w);
  *(s16x8*)(out + idx) = o;
}

__global__ void k_init(const float* __restrict__ h0, const int* __restrict__ mask_as_int,
                       char* __restrict__ ws) {
  int tid = blockIdx.x * blockDim.x + threadIdx.x;
  short* hb0 = (short*)(ws + WS_HS);
  for (int i = tid; i < BB * HH; i += gridDim.x * blockDim.x) hb0[i] = f2bf(h0[i]);
  if (blockIdx.x == 0) {
    int* cnt = (int*)(ws + WS_CNT);
    for (int i = threadIdx.x; i < 256; i += blockDim.x) cnt[i] = 0;
    int v = 0;
    for (int i = threadIdx.x; i < 4096; i += blockDim.x) v |= (mask_as_int[i] & ~1);
    __shared__ int red[256];
    red[threadIdx.x] = v;
    __syncthreads();
    if (threadIdx.x == 0) {
      int a = 0;
      for (int j = 0; j < 256; j++) a |= red[j];
      ((int*)(ws + WS_FLAG))[0] = (a != 0) ? 1 : 0;
      float* acc = (float*)(ws + WS_ACC);
      acc[0] = 0.f; acc[1] = 0.f;
    }
  }
}

// ---- bf16 MFMA GEMM: C[M][N] = A[M][K] * Bm[N][K]^T (+bias1+bias2), bf16 out ----
__global__ __launch_bounds__(256) void k_gemm(const short* __restrict__ A, int lda,
    const short* __restrict__ Bm, int ldb, int bcol0,
    short* __restrict__ C, int ldc, int ksteps,
    const float* __restrict__ bias1, const float* __restrict__ bias2) {
  int w = threadIdx.x >> 6, l = threadIdx.x & 63;
  int lc = l & 15, lq = l >> 4;
  int arow = blockIdx.x * 64 + w * 16 + lc;
  f32x4 acc[4];
  const f32x4 z = {0.f, 0.f, 0.f, 0.f};
#pragma unroll
  for (int i = 0; i < 4; i++) acc[i] = z;
  const short* ap = A + (size_t)arow * lda + lq * 8;
  for (int kk = 0; kk < ksteps; ++kk) {
    s16x8 a = *(const s16x8*)(ap + kk * 32);
#pragma unroll
    for (int nt = 0; nt < 4; ++nt) {
      int brow = blockIdx.y * 64 + nt * 16 + lc;
      s16x8 b = *(const s16x8*)(Bm + (size_t)brow * ldb + bcol0 + kk * 32 + lq * 8);
      acc[nt] = __builtin_amdgcn_mfma_f32_16x16x32_bf16(a, b, acc[nt], 0, 0, 0);
    }
  }
#pragma unroll
  for (int nt = 0; nt < 4; ++nt) {
    int col = blockIdx.y * 64 + nt * 16 + lc;
    float badd = (bias1 ? bias1[col] : 0.f) + (bias2 ? bias2[col] : 0.f);
#pragma unroll
    for (int j = 0; j < 4; j++) {
      int r = blockIdx.x * 64 + w * 16 + lq * 4 + j;
      C[(size_t)r * ldc + col] = f2bf(acc[nt][j] + badd);
    }
  }
}

// ---- persistent LSTM recurrence ----
// 256 WGs (1/CU), 512 threads. Group = 64 WGs over 64 batch rows (2 XCDs);
// each WG owns 16 hidden cols. Waves: (wy 0..3 row-slab 16) x (kh 0..1 k-half).
// Proven round-4/9 protocol (B1/B2/B3 + tid0 flag, sc0sc1 h-exchange).
// NEW: xproj stream eliminated. xbase (+biases) lives in act-thread registers
// (loaded once); per-step eproj[tok] gather by kh=1 waves: L2-resident loads
// issued post-B1, dumped to single-buffered LDS xbuf post-B2 (act waves read
// xbuf pre-B2 -> no race; B3 publishes for next step).
__global__ __launch_bounds__(512) void k_lstm(const float* __restrict__ Whh,
    const short* __restrict__ xbase, const short* __restrict__ eproj,
    const int* __restrict__ atruth, const float* __restrict__ c0,
    char* __restrict__ ws) {
  extern __shared__ char sm[];
  float* part = (float*)(sm + 131072);          // [4 wy][16 reg][64 lane] f32 = 16 KB
  short* xbuf = (short*)(sm + 131072 + 16384);  // [64 row][66 pad] bf16 = 8448 B
  const int bid = blockIdx.x;
  const int xcd = bid & 7, slot = bid >> 3;
  const int mg = xcd >> 1;                    // batch group 0..3
  const int hb = slot * 2 + (xcd & 1);        // hidden block 0..63
  const int wgid = (xcd & 1) * 32 + slot;     // id within group 0..63
  const int tid = threadIdx.x;
  const int w = tid >> 6, l = tid & 63;
  const int lc = l & 15, lq = l >> 4;
  const int wy = w & 3, kh = w >> 2;          // row-slab(16) / k-half(512)

  // stage W_hh slice -> LDS bf16 swizzled: row r=g*16+rl at r*2048, byte k ^ ((rl&7)<<4)
  {
    const int r = tid >> 3, q = tid & 7;
    const int g = r >> 4, rl = r & 15;
    const float* src = Whh + (size_t)(g * HH + hb * 16 + rl) * HH + q * 128;
    const int swz = (rl & 7) << 4;
    char* dst = sm + r * 2048;
#pragma unroll
    for (int i = 0; i < 128; i += 8) {
      float4 f0 = *(const float4*)(src + i);
      float4 f1 = *(const float4*)(src + i + 4);
      s16x8 o;
      o[0]=f2bf(f0.x); o[1]=f2bf(f0.y); o[2]=f2bf(f0.z); o[3]=f2bf(f0.w);
      o[4]=f2bf(f1.x); o[5]=f2bf(f1.y); o[6]=f2bf(f1.z); o[7]=f2bf(f1.w);
      int koff = (q * 128 + i) * 2;
      *(s16x8*)(dst + (koff ^ swz)) = o;
    }
  }

  const int colbase = hb * 16;
  short* hs = (short*)(ws + WS_HS);
  int* flags = (int*)(ws + WS_CNT);
  const int swzl = (lc & 7) << 4;
  const int row0 = mg * 64 + wy * 16;

  // c-state + xbase regs (kh=0 lanes): cell (row0 + lq*4 + j, colbase + lc)
  float cst[4], xbv[4][4];
  if (kh == 0) {
#pragma unroll
    for (int j = 0; j < 4; ++j) {
      const int b = row0 + lq * 4 + j;
      cst[j] = c0[(size_t)b * HH + colbase + lc];
#pragma unroll
      for (int g = 0; g < 4; ++g)
        xbv[g][j] = bf2f((unsigned short)xbase[(size_t)b * G4 + g * HH + colbase + lc]);
    }
  }
  // prologue gather: step-0 prev_tok = 0 for all rows
  if (kh == 1) {
    const int tid2 = tid - 256, grow = tid2 >> 2, ggate = tid2 & 3;
    const short* es = eproj + (size_t)ggate * HH + colbase;  // tok 0
    s16x8 e0 = *(const s16x8*)(es);
    s16x8 e1 = *(const s16x8*)(es + 8);
    *(s16x8*)(xbuf + grow * 66 + ggate * 16) = e0;
    *(s16x8*)(xbuf + grow * 66 + ggate * 16 + 8) = e1;
  }
  float* pslot = part + (size_t)wy * 1024 + l;  // + reg*64
  __syncthreads();

  for (int t = 0; t < TT; ++t) {
    if (t && w == 0) {  // wave-0 poll: all 64 group flags >= t
      const int* f = flags + mg * 64 + l;
      for (;;) {
        int v = load_int_cc(f);
        if (__all(v >= t)) break;
        __builtin_amdgcn_s_sleep(1);
      }
    }
    __syncthreads();  // B1: step-t h visible; xbuf[t] published

    // kh=1: issue next-step eproj gather (L2/IF$-resident; hides under MFMA)
    s16x8 e0, e1;
    if (kh == 1 && t + 1 < TT) {
      const int tid2 = tid - 256, grow = tid2 >> 2, ggate = tid2 & 3;
      int tokn = atruth[(mg * 64 + grow) * TT + t];
      const short* es = eproj + (size_t)tokn * G4 + ggate * HH + colbase;
      e0 = *(const s16x8*)(es);
      e1 = *(const s16x8*)(es + 8);
    }
    // kh=0: read this step's eproj slice from xbuf into regs (pre-B2 -> race-free)
    float exv[4][4];
    if (kh == 0) {
#pragma unroll
      for (int g = 0; g < 4; ++g)
#pragma unroll
        for (int j = 0; j < 4; ++j)
          exv[g][j] = bf2f((unsigned short)xbuf[(wy * 16 + lq * 4 + j) * 66 + g * 16 + lc]);
    }

    // MFMA: 4 gates x 16 rows x 16 cols over k-half kh (plain loads; compiler pipelines)
    const f32x4 z = {0.f, 0.f, 0.f, 0.f};
    f32x4 acc0 = z, acc1 = z, acc2 = z, acc3 = z;
    const short* arowp = hs + (size_t)t * (BB * HH) + (size_t)(row0 + lc) * HH + kh * 512 + lq * 8;
#pragma unroll
    for (int kk = 0; kk < 16; ++kk) {
      s16x8 a = *(const s16x8*)(arowp + kk * 32);
      const int kx = (((kh * 16 + kk) * 64) + lq * 16) ^ swzl;
      const char* bp = sm + lc * 2048 + kx;
      acc0 = __builtin_amdgcn_mfma_f32_16x16x32_bf16(a, *(const s16x8*)(bp), acc0, 0, 0, 0);
      acc1 = __builtin_amdgcn_mfma_f32_16x16x32_bf16(a, *(const s16x8*)(bp + 16 * 2048), acc1, 0, 0, 0);
      acc2 = __builtin_amdgcn_mfma_f32_16x16x32_bf16(a, *(const s16x8*)(bp + 32 * 2048), acc2, 0, 0, 0);
      acc3 = __builtin_amdgcn_mfma_f32_16x16x32_bf16(a, *(const s16x8*)(bp + 48 * 2048), acc3, 0, 0, 0);
    }

    // partial exchange: kh=1 writes b32 [reg][lane] (conflict-free)
    if (kh == 1) {
#pragma unroll
      for (int j = 0; j < 4; ++j) {
        pslot[(0 * 4 + j) * 64] = acc0[j];
        pslot[(1 * 4 + j) * 64] = acc1[j];
        pslot[(2 * 4 + j) * 64] = acc2[j];
        pslot[(3 * 4 + j) * 64] = acc3[j];
      }
    }
    __syncthreads();  // B2: partials ready; xbuf reads done

    if (kh == 0) {
#pragma unroll
      for (int j = 0; j < 4; ++j) {
        acc0[j] += pslot[(0 * 4 + j) * 64];
        acc1[j] += pslot[(1 * 4 + j) * 64];
        acc2[j] += pslot[(2 * 4 + j) * 64];
        acc3[j] += pslot[(3 * 4 + j) * 64];
      }
      short* hrow = hs + (size_t)(t + 1) * (BB * HH) +
                    (size_t)(row0 + lq * 4) * HH + colbase + lc;
#pragma unroll
      for (int j = 0; j < 4; ++j) {
        float pi = acc0[j] + exv[0][j] + xbv[0][j];
        float pf = acc1[j] + exv[1][j] + xbv[1][j];
        float pg = acc2[j] + exv[2][j] + xbv[2][j];
        float po = acc3[j] + exv[3][j] + xbv[3][j];
        float cv = fsig(pf) * cst[j] + fsig(pi) * ftanh(pg);
        cst[j] = cv;
        store_short_cc(hrow + (size_t)j * HH, (unsigned)(unsigned short)f2bf(fsig(po) * ftanh(cv)));
      }
    } else if (t + 1 < TT) {  // kh=1: dump next-step gather to xbuf (post-B2)
      const int tid2 = tid - 256, grow = tid2 >> 2, ggate = tid2 & 3;
      *(s16x8*)(xbuf + grow * 66 + ggate * 16) = e0;
      *(s16x8*)(xbuf + grow * 66 + ggate * 16 + 8) = e1;
    }
    asm volatile("s_waitcnt vmcnt(0)" ::: "memory");  // each wave drains own stores
    __syncthreads();                                   // B3: drained; xbuf published
    if (tid == 0 && t < TT - 1) store_dword_cc(flags + mg * 64 + wgid, t + 1);
  }
}

// ---- logits + fused log-softmax + masked NLL partial sums ----
__global__ __launch_bounds__(256, 1) void k_logits(const short* __restrict__ hsb,
    const short* __restrict__ Wo, const float* __restrict__ bout,
    const int* __restrict__ atruth, const void* __restrict__ maskp,
    char* __restrict__ ws) {
  extern __shared__ char sm[];
  const int tid = threadIdx.x;
  const int w = tid >> 6, l = tid & 63;
  const int lc = l & 15, lq = l >> 4;
  const int rowbase = blockIdx.x * 64 + w * 16;
  f32x4 acc[32];
#pragma unroll
  for (int nt = 0; nt < 32; ++nt) {
    float bv = bout[nt * 16 + lc];
    f32x4 tmp = {bv, bv, bv, bv};
    acc[nt] = tmp;
  }
  const int swzl = (lc & 7) << 4;
  for (int kb = 0; kb < 16; ++kb) {
    __syncthreads();
    {
      const int r0 = tid >> 3, q = tid & 7;
#pragma unroll
      for (int i = 0; i < 16; i++) {
        int r = r0 + 32 * i;
        s16x8 v = *(const s16x8*)(Wo + (size_t)r * HH + kb * 64 + q * 8);
        *(s16x8*)(sm + r * 128 + ((q * 16) ^ ((r & 7) << 4))) = v;
      }
    }
    __syncthreads();
#pragma unroll
    for (int ks = 0; ks < 2; ++ks) {
      s16x8 a = *(const s16x8*)(hsb + (size_t)(rowbase + lc) * HH + kb * 64 + ks * 32 + lq * 8);
      const int kx = (ks * 64 + lq * 16) ^ swzl;
#pragma unroll
      for (int nt = 0; nt < 32; ++nt) {
        s16x8 b = *(const s16x8*)(sm + (nt * 16 + lc) * 128 + kx);
        acc[nt] = __builtin_amdgcn_mfma_f32_16x16x32_bf16(a, b, acc[nt], 0, 0, 0);
      }
    }
  }
  const int bytemode = ((const int*)(ws + WS_FLAG))[0];
  const unsigned char* mb = (const unsigned char*)maskp;
  const int* mi = (const int*)maskp;
  float nlls = 0.f, cnts = 0.f;
#pragma unroll
  for (int j = 0; j < 4; j++) {
    int gr = rowbase + lq * 4 + j;
    int tt = gr >> 8, b = gr & 255;
    float m = -1e30f;
#pragma unroll
    for (int nt = 0; nt < 32; ++nt) m = fmaxf(m, acc[nt][j]);
    m = fmaxf(m, __shfl_xor(m, 1)); m = fmaxf(m, __shfl_xor(m, 2));
    m = fmaxf(m, __shfl_xor(m, 4)); m = fmaxf(m, __shfl_xor(m, 8));
    float s = 0.f;
#pragma unroll
    for (int nt = 0; nt < 32; ++nt) s += __expf(acc[nt][j] - m);
    s += __shfl_xor(s, 1); s += __shfl_xor(s, 2);
    s += __shfl_xor(s, 4); s += __shfl_xor(s, 8);
    float lse = m + __logf(s);
    int tg = atruth[b * TT + tt];
    int mk = bytemode ? (int)mb[b * TT + tt] : mi[b * TT + tt];
    if (((tg & 15) == lc) && mk) {
      float tl = 0.f;
#pragma unroll
      for (int nt = 0; nt < 32; ++nt) if (nt == (tg >> 4)) tl = acc[nt][j];
      nlls += (lse - tl);
    }
    if (lc == 0 && mk) cnts += 1.f;
  }
#pragma unroll
  for (int off = 1; off < 64; off <<= 1) {
    nlls += __shfl_xor(nlls, off);
    cnts += __shfl_xor(cnts, off);
  }
  if (l == 0) {
    float* accf = (float*)(ws + WS_ACC);
    atomicAdd(&accf[0], nlls);
    atomicAdd(&accf[1], cnts);
  }
}

__global__ void k_final(const char* __restrict__ ws, float* __restrict__ out) {
  const float* accf = (const float*)(ws + WS_ACC);
  out[0] = accf[0] / accf[1];
}

extern "C" void kernel_launch(void* const* d_in, const int* in_sizes, int n_in,
                              void* d_out, int out_size, void* d_ws, size_t ws_size,
                              hipStream_t stream) {
  const float* x      = (const float*)d_in[0];
  const int*   atruth = (const int*)d_in[1];
  const void*  amask  = d_in[2];
  const float* emb    = (const float*)d_in[3];
  const float* W_ih   = (const float*)d_in[4];
  const float* W_hh   = (const float*)d_in[5];
  const float* b_ih   = (const float*)d_in[6];
  const float* b_hh   = (const float*)d_in[7];
  const float* W_out  = (const float*)d_in[8];
  const float* b_out  = (const float*)d_in[9];
  const float* h0     = (const float*)d_in[10];
  const float* c0     = (const float*)d_in[11];
  char* ws = (char*)d_ws;
  float* out = (float*)d_out;

  hipFuncSetAttribute((const void*)k_lstm, hipFuncAttributeMaxDynamicSharedMemorySize, 155904);
  hipFuncSetAttribute((const void*)k_logits, hipFuncAttributeMaxDynamicSharedMemorySize, 65536);

  k_f2bf8<<<dim3((G4 * DINk / 8 + 255) / 256), 256, 0, stream>>>(W_ih, (short*)(ws + WS_WIH), G4 * DINk / 8);
  k_f2bf8<<<dim3((NTAG * HH / 8 + 255) / 256), 256, 0, stream>>>(W_out, (short*)(ws + WS_WOUT), NTAG * HH / 8);
  k_f2bf8<<<dim3((BB * XD / 8 + 255) / 256), 256, 0, stream>>>(x, (short*)(ws + WS_XBF), BB * XD / 8);
  k_f2bf8<<<dim3((NTAG * CCG / 8 + 255) / 256), 256, 0, stream>>>(emb, (short*)(ws + WS_EMBBF), NTAG * CCG / 8);

  k_init<<<64, 256, 0, stream>>>(h0, (const int*)amask, ws);

  // xbase = x @ W_ih[:, :512]^T + b_ih + b_hh    [256, 4096] bf16
  k_gemm<<<dim3(4, 64), 256, 0, stream>>>((short*)(ws + WS_XBF), XD, (short*)(ws + WS_WIH), DINk, 0,
                                          (short*)(ws + WS_XBASE), G4, XD / 32, b_ih, b_hh);
  // eproj = emb @ W_ih[:, 512:]^T                [512, 4096] bf16
  k_gemm<<<dim3(8, 64), 256, 0, stream>>>((short*)(ws + WS_EMBBF), CCG, (short*)(ws + WS_WIH), DINk, XD,
                                          (short*)(ws + WS_EPROJ), G4, CCG / 32, nullptr, nullptr);

  k_lstm<<<256, 512, 155904, stream>>>(W_hh, (const short*)(ws + WS_XBASE),
                                       (const short*)(ws + WS_EPROJ), atruth, c0, ws);

  k_logits<<<256, 256, 65536, stream>>>((short*)(ws + WS_HS) + BB * HH, (short*)(ws + WS_WOUT), b_out,
                                        atruth, amask, ws);
  k_final<<<1, 1, 0, stream>>>(ws, out);
}